// Round 1
// 694.899 us; speedup vs baseline: 1.0209x; 1.0209x over previous
//
#include <hip/hip_runtime.h>
#include <stdint.h>

// ---------------- problem constants ----------------
#define B_   4
#define A_   25200
#define NC_  80
#define ROW_ 85          // 5 + NC
#define ATT_ 980         // 5 * 14 * 14
#define MAXDET_ 100
#define TOPK_ 1024
#define CAP_  4096       // candidate buffer per batch (expected ~1.6K)
#define OUTSTRIDE_ 25606 // 4 + 1 + 1 + 160*160
#define HW_ 160
#define HWHW_ 25600
#define CONF_ 0.25f
#define IOUT_ 0.45f

// ---------------- workspace layout (bytes) ----------------
#define WS_HIST 0         // 4 * 256 u32 = 4096
#define WS_CNT  4096      // 4 u32
#define WS_CAND 8192      // 4 * 4096 u64 -> [8192, 139264)
#define WS_DETA 139264    // 400 i32 (selected anchor per det slot)
// total ~141 KB

typedef unsigned long long u64;
typedef unsigned u32;

// ---------------- K0: clear hist + counters ----------------
__global__ void k_clear(char* w) {
    int i = blockIdx.x * 256 + threadIdx.x;
    if (i < 1028) ((u32*)w)[i] = 0u;   // hist (1024 words) + cnt (4 words)
}

// ---------------- K1: score histogram (float-bit buckets) ----------------
__global__ void k_hist(const float* __restrict__ test, char* __restrict__ w) {
    int b = blockIdx.y;
    __shared__ u32 h[256];
    if (threadIdx.x < 256) h[threadIdx.x] = 0u;
    __syncthreads();
    const int total = A_ * NC_;
    for (int e = blockIdx.x * 256 + threadIdx.x; e < total; e += 128 * 256) {
        u32 a = (u32)e / 80u;
        u32 c = (u32)e - a * 80u;
        const float* row = test + ((size_t)b * A_ + a) * ROW_;
        float s = row[5 + c] * row[4];
        if (s > CONF_) {
            u32 key = __float_as_uint(s);
            int wb = (int)(key >> 17) - 7936;
            wb = wb < 0 ? 0 : (wb > 255 ? 255 : wb);
            atomicAdd(&h[wb], 1u);
        }
    }
    __syncthreads();
    u32* hist = (u32*)(w + WS_HIST);
    if (threadIdx.x < 256 && h[threadIdx.x]) atomicAdd(&hist[b * 256 + threadIdx.x], h[threadIdx.x]);
}

// ---------------- K2: collect candidates >= threshold bucket ----------------
// threshold bucket computed redundantly per block via LDS suffix-scan (removes
// the old 1-block k_thresh kernel; kernel boundary after k_hist guarantees
// histogram visibility, no fence games needed).
__global__ void k_collect(const float* __restrict__ test, char* __restrict__ w) {
    int b = blockIdx.y;
    __shared__ u32 s[256];
    __shared__ int swtb;
    const u32* hist = (const u32*)(w + WS_HIST) + (size_t)b * 256;
    if (threadIdx.x < 256) s[threadIdx.x] = hist[threadIdx.x];
    if (threadIdx.x == 0) swtb = 0;
    __syncthreads();
    // Hillis-Steele suffix sums: s[i] = sum_{k>=i} h[k]
    for (int off = 1; off < 256; off <<= 1) {
        u32 v = 0;
        if (threadIdx.x < 256) {
            v = s[threadIdx.x];
            if (threadIdx.x + off < 256) v += s[threadIdx.x + off];
        }
        __syncthreads();
        if (threadIdx.x < 256) s[threadIdx.x] = v;
        __syncthreads();
    }
    if (threadIdx.x < 256) {
        u32 Si = s[threadIdx.x];
        u32 Sn = (threadIdx.x == 255) ? 0u : s[threadIdx.x + 1];
        // wtb = max i with suffix(i) >= TOPK  (exactly one thread matches)
        if (Si >= TOPK_ && Sn < TOPK_) swtb = threadIdx.x;
    }
    __syncthreads();
    int wtb = swtb;

    u32* cnt = (u32*)(w + WS_CNT);
    u64* cand = (u64*)(w + WS_CAND);
    const int total = A_ * NC_;
    for (int e = blockIdx.x * 256 + threadIdx.x; e < total; e += 128 * 256) {
        u32 a = (u32)e / 80u;
        u32 c = (u32)e - a * 80u;
        const float* row = test + ((size_t)b * A_ + a) * ROW_;
        float sc = row[5 + c] * row[4];
        if (sc > CONF_) {
            u32 key = __float_as_uint(sc);
            int wb = (int)(key >> 17) - 7936;
            wb = wb < 0 ? 0 : (wb > 255 ? 255 : wb);
            if (wb >= wtb) {
                u32 pos = atomicAdd(&cnt[b], 1u);
                if (pos < CAP_)
                    cand[(size_t)b * CAP_ + pos] = ((u64)key << 32) | (u64)(0xFFFFFFFFu - (u32)e);
            }
        }
    }
}

// exact-numpy IoU suppression test (no FMA contraction -> matches np bitwise)
__device__ __forceinline__ bool sup_pair(float4 a, float4 b, int ca, int cbb) {
#pragma clang fp contract(off)
    if (ca != cbb) return false;
    float areaA = fmaxf(a.z - a.x, 0.f) * fmaxf(a.w - a.y, 0.f);
    float areaB = fmaxf(b.z - b.x, 0.f) * fmaxf(b.w - b.y, 0.f);
    float ltx = fmaxf(a.x, b.x), lty = fmaxf(a.y, b.y);
    float rbx = fminf(a.z, b.z), rby = fminf(a.w, b.w);
    float iw = fmaxf(rbx - ltx, 0.f), ih = fmaxf(rby - lty, 0.f);
    float inter = iw * ih;
    float iou = inter / (((areaA + areaB) - inter) + 1e-9f);
    return iou > IOUT_;
}

// ---------------- K3: per-batch sort + in-LDS greedy NMS + header writes ----
// Replaces the old k_sort + k_sup (1024x1024 bit-matrix, 512KB global
// round-trip) + k_nms (serial global-latency chain) trio. After the bitonic
// sort everything needed lives in LDS; greedy NMS computes suppression
// on-demand (only ~100 selected rows x 1024 pairs instead of 1024x1024).
__global__ __launch_bounds__(1024) void k_sortnms(const float* __restrict__ test,
                                                  char* __restrict__ w,
                                                  float* __restrict__ out) {
    int b = blockIdx.x;
    int tid = threadIdx.x;
    __shared__ u64 sm[CAP_];          // 32 KB
    __shared__ float4 cbs[TOPK_];     // 16 KB
    __shared__ float tvs[TOPK_];      // 4 KB
    __shared__ int tcs[TOPK_];        // 4 KB
    __shared__ int tas[TOPK_];        // 4 KB
    __shared__ u64 wmask[16];
    __shared__ int selA[MAXDET_];
    __shared__ u32 okA[MAXDET_];
    __shared__ int sj;

    u32 cnt = ((const u32*)(w + WS_CNT))[b];
    int n = cnt < CAP_ ? (int)cnt : CAP_;
    int n2 = 1024;                     // dynamic bitonic width (pow2 >= n)
    while (n2 < n) n2 <<= 1;
    const u64* cand = (const u64*)(w + WS_CAND) + (size_t)b * CAP_;
    for (int i = tid; i < n2; i += 1024) sm[i] = (i < n) ? cand[i] : 0ull;
    __syncthreads();
    // bitonic sort, descending (key desc, then smaller idx first via ~idx low)
    for (int k = 2; k <= n2; k <<= 1) {
        for (int j = k >> 1; j > 0; j >>= 1) {
            for (int t = tid; t < n2; t += 1024) {
                int ixj = t ^ j;
                if (ixj > t) {
                    u64 a = sm[t], c = sm[ixj];
                    bool desc = ((t & k) == 0);
                    if (desc ? (a < c) : (a > c)) { sm[t] = c; sm[ixj] = a; }
                }
            }
            __syncthreads();
        }
    }
    int ntop = n < TOPK_ ? n : TOPK_;
    // decode top-1024 into LDS arrays (one candidate per thread)
    {
        int i = tid;
        if (i < ntop) {
            u64 v = sm[i];
            u32 key = (u32)(v >> 32);
            u32 idx = 0xFFFFFFFFu - (u32)(v & 0xFFFFFFFFull);
            u32 anchor = idx / 80u;
            u32 cls = idx - anchor * 80u;
            const float* tr = test + ((size_t)b * A_ + anchor) * ROW_;
            float cx = tr[0], cy = tr[1], ww = tr[2], hh = tr[3];
            float4 box;
            box.x = cx - 0.5f * ww; box.y = cy - 0.5f * hh;
            box.z = cx + 0.5f * ww; box.w = cy + 0.5f * hh;
            tvs[i] = __uint_as_float(key);
            tas[i] = (int)anchor; tcs[i] = (int)cls; cbs[i] = box;
        } else {
            tvs[i] = 0.f; tas[i] = 0; tcs[i] = 0;
            cbs[i] = make_float4(0.f, 0.f, 0.f, 0.f);
        }
    }
    __syncthreads();

    // greedy NMS: thread i owns candidate i (sorted desc => first valid = argmax,
    // ties already broken by smaller flat index, matching jnp.argmax)
    bool valid = (tid < ntop);
    float4 myb = cbs[tid];
    int myc = tcs[tid];
    for (int k = 0; k < MAXDET_; ++k) {
        u64 bal = __ballot(valid);
        if ((tid & 63) == 0) wmask[tid >> 6] = bal;
        __syncthreads();
        if (tid == 0) {
            int j = -1;
            for (int wv = 15; wv >= 0; --wv) {   // backward, last-write-wins => lowest wave
                u64 m = wmask[wv];
                if (m) j = (wv << 6) + (__ffsll(m) - 1);
            }
            sj = j;
            selA[k] = j < 0 ? 0 : j;
            okA[k] = j < 0 ? 0u : 1u;
        }
        __syncthreads();
        int j = sj;
        if (j >= 0 && valid) {
            if (tid == j || sup_pair(cbs[j], myb, tcs[j], myc)) valid = false;
        }
    }
    __syncthreads();

    // write detection headers + selected anchors
    int* deta = (int*)(w + WS_DETA);
    for (int k = tid; k < MAXDET_; k += 1024) {
        int ok = (int)okA[k], s = selA[k];
        float b0 = 0, b1 = 0, b2 = 0, b3 = 0, sc = 0; int cls_ = 0, anc = 0;
        if (ok) {
            float4 bb = cbs[s];
            b0 = bb.x; b1 = bb.y; b2 = bb.z; b3 = bb.w;
            sc = tvs[s]; cls_ = tcs[s]; anc = tas[s];
        }
        size_t o = ((size_t)(b * MAXDET_ + k)) * OUTSTRIDE_;
        out[o + 0] = b0; out[o + 1] = b1; out[o + 2] = b2; out[o + 3] = b3;
        out[o + 4] = sc; out[o + 5] = (float)cls_;
        deta[b * MAXDET_ + k] = anc;
    }
}

// ---------------- K4: ROI-align + coeff-resize + softmax + sigmoid masks ----
__global__ void k_mask(const float* __restrict__ test, const float* __restrict__ attn,
                       const float* __restrict__ bases, const float* __restrict__ sem,
                       const char* __restrict__ w, float* __restrict__ out) {
    int roi = blockIdx.x;          // 0..399
    int b = roi / MAXDET_;
    int anchor = ((const int*)(w + WS_DETA))[roi];
    const float* t = test + ((size_t)b * A_ + anchor) * ROW_;
    float cx = t[0], cy = t[1], ww = t[2], hh = t[3];
    float bx1 = cx - 0.5f * ww, by1 = cy - 0.5f * hh;
    float bx2 = cx + 0.5f * ww, by2 = cy + 0.5f * hh;
    float rx1 = bx1 * 0.25f - 0.5f, ry1 = by1 * 0.25f - 0.5f;
    float rx2 = bx2 * 0.25f - 0.5f, ry2 = by2 * 0.25f - 0.5f;
    float xstep = (rx2 - rx1) / 160.f, ystep = (ry2 - ry1) / 160.f;

    __shared__ float att[5 * 196];
    __shared__ float sxw[HW_], syw[HW_], rzw[HW_];
    __shared__ int sxlo[HW_], sxhi[HW_], sylo[HW_], syhi[HW_];
    __shared__ int sxv[HW_], syv[HW_], rzlo[HW_];

    const float* arow = attn + ((size_t)b * A_ + anchor) * ATT_;
    for (int i = threadIdx.x; i < ATT_; i += 256) att[i] = arow[i];
    if (threadIdx.x < HW_) {
        int i = threadIdx.x;
        float coord = rx1 + (i + 0.5f) * xstep;
        sxv[i] = (coord > -1.0f) && (coord < 160.0f);
        float c = fminf(fmaxf(coord, 0.f), 159.f);
        float lo = floorf(c);
        sxlo[i] = (int)lo; sxhi[i] = min((int)lo + 1, 159); sxw[i] = c - lo;
        coord = ry1 + (i + 0.5f) * ystep;
        syv[i] = (coord > -1.0f) && (coord < 160.0f);
        c = fminf(fmaxf(coord, 0.f), 159.f);
        lo = floorf(c);
        sylo[i] = (int)lo; syhi[i] = min((int)lo + 1, 159); syw[i] = c - lo;
        // 14 -> 160 half-pixel linear resize (clamped == jax normalized triangle)
        float f = (i + 0.5f) * (14.f / 160.f) - 0.5f;
        float rc = fminf(fmaxf(f, 0.f), 13.f);
        float rlo = floorf(rc);
        rzlo[i] = (int)rlo; rzw[i] = rc - rlo;
    }
    __syncthreads();

    const float* bp[5];
    bp[0] = bases + ((size_t)b * 4 + 0) * HWHW_;
    bp[1] = bases + ((size_t)b * 4 + 1) * HWHW_;
    bp[2] = bases + ((size_t)b * 4 + 2) * HWHW_;
    bp[3] = bases + ((size_t)b * 4 + 3) * HWHW_;
    bp[4] = sem + (size_t)b * HWHW_;

    size_t obase = (size_t)roi * OUTSTRIDE_ + 6;
    int pstart = blockIdx.y * (HWHW_ / 8);
    int pend = pstart + (HWHW_ / 8);
    for (int p = pstart + (int)threadIdx.x; p < pend; p += 256) {
        int y = p / HW_, x = p - y * HW_;
        int ylo = sylo[y], yhi = syhi[y]; float wy = syw[y];
        int xlo = sxlo[x], xhi = sxhi[x]; float wx = sxw[x];
        bool v = sxv[x] && syv[y];
        float w00 = (1.f - wy) * (1.f - wx), w01 = (1.f - wy) * wx;
        float w10 = wy * (1.f - wx), w11 = wy * wx;
        int i00 = ylo * HW_ + xlo, i01 = ylo * HW_ + xhi;
        int i10 = yhi * HW_ + xlo, i11 = yhi * HW_ + xhi;
        float pooled[5];
#pragma unroll
        for (int c5 = 0; c5 < 5; ++c5) {
            float g = bp[c5][i00] * w00 + bp[c5][i01] * w01 + bp[c5][i10] * w10 + bp[c5][i11] * w11;
            pooled[c5] = v ? g : 0.f;
        }
        int cylo = rzlo[y]; float cwy = rzw[y]; int cyhi = min(cylo + 1, 13);
        int cxlo = rzlo[x]; float cwx = rzw[x]; int cxhi = min(cxlo + 1, 13);
        float c00 = (1.f - cwy) * (1.f - cwx), c01 = (1.f - cwy) * cwx;
        float c10 = cwy * (1.f - cwx), c11 = cwy * cwx;
        int j00 = cylo * 14 + cxlo, j01 = cylo * 14 + cxhi;
        int j10 = cyhi * 14 + cxlo, j11 = cyhi * 14 + cxhi;
        float cf[5]; float m = -1e30f;
#pragma unroll
        for (int c5 = 0; c5 < 5; ++c5) {
            const float* ap = att + c5 * 196;
            float g = ap[j00] * c00 + ap[j01] * c01 + ap[j10] * c10 + ap[j11] * c11;
            cf[c5] = g; m = fmaxf(m, g);
        }
        float se = 0.f, dot = 0.f;
#pragma unroll
        for (int c5 = 0; c5 < 5; ++c5) {
            float e = __expf(cf[c5] - m);
            se += e; dot += pooled[c5] * e;
        }
        dot /= se;
        out[obase + p] = 1.f / (1.f + __expf(-dot));
    }
}

extern "C" void kernel_launch(void* const* d_in, const int* in_sizes, int n_in,
                              void* d_out, int out_size, void* d_ws, size_t ws_size,
                              hipStream_t stream) {
    const float* test = (const float*)d_in[0];
    const float* attn = (const float*)d_in[1];
    const float* bases = (const float*)d_in[2];
    const float* sem = (const float*)d_in[3];
    float* out = (float*)d_out;
    char* w = (char*)d_ws;   // needs ~141 KB

    k_clear<<<5, 256, 0, stream>>>(w);
    k_hist<<<dim3(128, B_), 256, 0, stream>>>(test, w);
    k_collect<<<dim3(128, B_), 256, 0, stream>>>(test, w);
    k_sortnms<<<B_, 1024, 0, stream>>>(test, w, out);
    k_mask<<<dim3(B_ * MAXDET_, 8), 256, 0, stream>>>(test, attn, bases, sem, w, out);
}